// Round 7
// baseline (164.104 us; speedup 1.0000x reference)
//
#include <hip/hip_runtime.h>
#include <cstdint>

typedef unsigned short ushort_t;

#define M_ROWS 4096
#define N_COLS 3072
#define K_DIM  1024
#define S_LEN  2048
#define NHEADS 16
#define HDIM   64
#define QSCALE 0.1803368801111204f  /* (1/sqrt(64)) * log2(e) */

typedef __bf16 bf16_t;
typedef bf16_t  bf16x8  __attribute__((ext_vector_type(8)));
typedef short   shortx4 __attribute__((ext_vector_type(4)));
typedef float   floatx4 __attribute__((ext_vector_type(4)));
typedef ushort_t ushortx4 __attribute__((ext_vector_type(4)));

union U32x2S4 { unsigned u[2]; shortx4 s; };

__device__ __forceinline__ unsigned short f2bf(float f) {
  unsigned u = __float_as_uint(f);
  u += 0x7FFFu + ((u >> 16) & 1u);
  return (unsigned short)(u >> 16);
}

// pack two fp32 -> two bf16 in one u32: low=a, high=b (fallback: round-half-up)
__device__ __forceinline__ unsigned pkbf(float a, float b) {
  unsigned ua = __float_as_uint(a) + 0x8000u;
  unsigned ub = __float_as_uint(b) + 0x8000u;
  return __builtin_amdgcn_perm(ub, ua, 0x07060302u);
}

// packed bf16 convert: single v_cvt_pk_bf16_f32 on gfx950 if available
__device__ __forceinline__ unsigned cvtpk(float a, float b) {
#if __has_builtin(__builtin_amdgcn_cvt_pk_bf16_f32)
  auto t = __builtin_amdgcn_cvt_pk_bf16_f32(a, b);
  unsigned r;
  __builtin_memcpy(&r, &t, 4);
  return r;
#else
  return pkbf(a, b);
#endif
}

__device__ __forceinline__ float fexp2(float x) {
#if __has_builtin(__builtin_amdgcn_exp2f)
  return __builtin_amdgcn_exp2f(x);
#else
  float r; asm volatile("v_exp_f32 %0, %1\n\ts_nop 1" : "=v"(r) : "v"(x)); return r;
#endif
}

__device__ __forceinline__ void gload_lds16(const void* g, void* l) {
  __builtin_amdgcn_global_load_lds(
      (const __attribute__((address_space(1))) unsigned int*)g,
      (__attribute__((address_space(3))) unsigned int*)l,
      16, 0, 0);
}

/* ------------------------ fp32 -> bf16 convert (v2: 32B/thread) ---------- */
__global__ __launch_bounds__(256) void cvt_bf16_kernel(
    const float* __restrict__ x, const float* __restrict__ w,
    ushort_t* __restrict__ Xb, ushort_t* __restrict__ Wb) {
  const int NX8 = (M_ROWS * K_DIM) / 8;
  int i = blockIdx.x * 256 + threadIdx.x;
  const float4* src;
  ushort_t* dst;
  int idx;
  if (i < NX8) { src = (const float4*)x; dst = Xb; idx = i; }
  else         { src = (const float4*)w; dst = Wb; idx = i - NX8; }
  float4 a = src[2 * idx];
  float4 b = src[2 * idx + 1];
  uint4 o;
  o.x = cvtpk(a.x, a.y);
  o.y = cvtpk(a.z, a.w);
  o.z = cvtpk(b.x, b.y);
  o.w = cvtpk(b.z, b.w);
  *(uint4*)(dst + 8 * (size_t)idx) = o;
}

/* ------------------------ QKV GEMM (r3 version — empirically best) --------
   m97 structure + LDS XOR chunk swizzle (chunk' = chunk ^ (row&7)),
   conflict-free (verified r3: SQ_LDS_BANK_CONFLICT -> 0). Scalar-store
   epilogue; r4's "vectorized" variant coincided with +13us rest — reverted.
   DO NOT MODIFY without counters (surfaces in top-5 once attn < gemm). */
__global__ __launch_bounds__(256) void qkv_gemm_kernel(
    const ushort_t* __restrict__ Xb, const ushort_t* __restrict__ Wb,
    const float* __restrict__ bias,
    ushort_t* __restrict__ Qb, ushort_t* __restrict__ Kb, ushort_t* __restrict__ Vb) {
  __shared__ ushort_t As[128 * 64];
  __shared__ ushort_t Bs[128 * 64];
  const int tid = threadIdx.x;
  const int l = tid & 63, w = tid >> 6;
  const int quad = l >> 4, lj = l & 15;
  const int m0 = blockIdx.y * 128, n0 = blockIdx.x * 128;
  const int wm = (w & 1) * 64, wn = (w >> 1) * 64;

  floatx4 acc[4][4] = {};

  const int srow = w * 32 + (l >> 3);
  const int scol = ((l & 7) ^ (l >> 3)) * 8; /* swizzled source chunk */
  const ushort_t* gA = Xb + (size_t)(m0 + srow) * K_DIM + scol;
  const ushort_t* gB = Wb + (size_t)(n0 + srow) * K_DIM + scol;
  ushort_t* lA = As + (w * 32) * 64;
  ushort_t* lB = Bs + (w * 32) * 64;

  const int swr = lj & 7;

  for (int k0 = 0; k0 < K_DIM; k0 += 64) {
    __syncthreads();
#pragma unroll
    for (int c = 0; c < 4; ++c) {
      gload_lds16(gA + (size_t)(c * 8) * K_DIM + k0, lA + c * 8 * 64);
      gload_lds16(gB + (size_t)(c * 8) * K_DIM + k0, lB + c * 8 * 64);
    }
    __syncthreads();
#pragma unroll
    for (int kk = 0; kk < 2; ++kk) {
      const int ch = ((kk * 4 + quad) ^ swr) * 8;
      bf16x8 aF[4], bF[4];
#pragma unroll
      for (int i = 0; i < 4; ++i)
        aF[i] = *(const bf16x8*)(As + (wm + i * 16 + lj) * 64 + ch);
#pragma unroll
      for (int j = 0; j < 4; ++j)
        bF[j] = *(const bf16x8*)(Bs + (wn + j * 16 + lj) * 64 + ch);
#pragma unroll
      for (int i = 0; i < 4; ++i)
#pragma unroll
        for (int j = 0; j < 4; ++j)
          acc[i][j] = __builtin_amdgcn_mfma_f32_16x16x32_bf16(aF[i], bF[j], acc[i][j], 0, 0, 0);
    }
  }

  /* epilogue: n = h*192 + r; r<64 -> Q, r<128 -> K, else V */
#pragma unroll
  for (int j = 0; j < 4; ++j) {
    const int n = n0 + wn + j * 16 + lj;
    const int h = n / 192;
    const int r = n - h * 192;
    const int seg = r >> 6;
    const int d = r & 63;
    const float bv = bias[n];
    ushort_t* dst = (seg == 0) ? Qb : (seg == 1) ? Kb : Vb;
    const float scl = (seg == 0) ? QSCALE : 1.0f;
    const size_t base = (size_t)h * S_LEN * HDIM + d;
#pragma unroll
    for (int i = 0; i < 4; ++i) {
#pragma unroll
      for (int rg = 0; rg < 4; ++rg) {
        const int m = m0 + wm + i * 16 + quad * 4 + rg;
        const int bi = m >> 11;
        const int si = m & 2047;
        dst[base + ((size_t)bi * NHEADS * S_LEN + si) * HDIM] =
            f2bf((acc[i][j][rg] + bv) * scl);
      }
    }
  }
}

/* ------------------------ flash attention (v10: double-buffered) ----------
   HISTORY: v4.1 (K,V in LDS, 2 barriers/iter) = 53.2us. v5-v8 K-from-
   global = 137-154us regardless of schedule (structurally dead).
   v9 = v4.1 + swizzle + setprio = 55.6us: swizzle re-proven on FETCH
   (12.3MB) but setprio suspected -2.4us (8-wave lockstep blocks = m190's
   GEMM-null case, not m191's phase-diverse case) -> REMOVED.
   v10 = T3-minimum 2-phase double-buffer. Counter model: LDS pipe =
   16 b128 (K) + 32 b64 (V) ~ 416cy/wave-iter x 16 waves x 16 iters
   ~ 44us/CU = the floor; v9's extra ~11us = stage->compute
   serialization (2 barriers/iter + V-latency exposed at barrier 2).
   New iter shape (ONE barrier): issue V loads(kb+1) + K DMA(kb+1) ->
   QK+softmax on buf[cur] (V latency drains under ~2000cy of MFMA/exp2,
   T14 issue-early/write-late) -> V perm+write to buf[cur^1] -> PV on
   buf[cur] -> __syncthreads (its vmcnt(0) drain finds K DMA long done).
   Single barrier also serializes buffer reuse correctly: all waves done
   READING buf[x] at iter kb-1 before any wave WRITES buf[x] at iter kb.
   LDS 2x(16+17.5K) = 68.6KB/block -> still 2 blocks/CU (137<160KB).
   Predicted: attn 55.6 -> 45-49, LDS_Block_Size 34304 -> 68608, VGPR
   ~64-72. Falsifier: attn >= 53 with dbuf confirmed => overlap wasn't
   the gap; next lever = fewer LDS bytes (V b64->b128 repack), not
   more overlap.
   NOTE (r5 lesson): 32q/wave caps at 8 waves/CU and regressed 2x. */
__global__ __launch_bounds__(512, 4) void attn_kernel(
    const ushort_t* __restrict__ Qb, const ushort_t* __restrict__ Kb,
    const ushort_t* __restrict__ Vb, float* __restrict__ out) {
  __shared__ ushort_t Ks[2][128 * 64];
  __shared__ ushort_t Vs[2][64 * 140];
  const int tid = threadIdx.x;
  const int l = tid & 63, w = tid >> 6;
  const int quad = l >> 4, lj = l & 15;
  /* XCD swizzle: HW round-robins wg -> XCD (idx%8). Remap so XCD x
     processes ids [x*64, x*64+64) = bh 4x..4x+3 -> per-XCD K/V working
     set ~2MB, L2-resident. 512%8==0 -> bijective. Verified r2/r6:
     FETCH 69.6 -> 12.3MB. */
  const int id = (blockIdx.x & 7) * 64 + (blockIdx.x >> 3);
  const int bh = id >> 4;
  const int qt = id & 15;
  const int q0 = qt * 128 + w * 16;
  const size_t headoff = (size_t)bh * S_LEN * HDIM;

  /* Q fragments: B-operand, n=q=lj, k = kk*32 + quad*8 + j */
  bf16x8 qF[2];
#pragma unroll
  for (int kk = 0; kk < 2; ++kk)
    qF[kk] = *(const bf16x8*)(Qb + headoff + (size_t)(q0 + lj) * HDIM +
                              kk * 32 + quad * 8);

  floatx4 accO[4] = {};
  float l_runA = 0.f, l_runB = 0.f;

  /* K staging with swizzled source chunk; LDS dest stays lane-contiguous */
  const int kr = tid >> 3;
  const int kc = ((tid & 7) ^ (kr & 7)) * 8;
  const ushort_t* gK = Kb + headoff + (size_t)kr * HDIM + kc;

  /* V staging: thread covers (s pair 2sp..2sp+1) x (d quad 4dq..4dq+3), R=0,1 */
  const int dq = tid & 15;
  const int spw = tid >> 4; /* 0..31 */
  const ushort_t* gV = Vb + headoff + dq * 4;
  const int swz = (dq >> 2) << 1; /* V swizzle in u32-column units */

  const int swk = lj & 7;

  /* ---- prologue: stage tile 0 into buffer 0 ---- */
  {
    uint2 va[2], vb[2];
#pragma unroll
    for (int R = 0; R < 2; ++R) {
      const ushort_t* g = gV + (size_t)(2 * (R * 32 + spw)) * HDIM;
      va[R] = *(const uint2*)g;
      vb[R] = *(const uint2*)(g + HDIM);
    }
#pragma unroll
    for (int c = 0; c < 2; ++c)
      gload_lds16(gK + (size_t)(c * 64) * HDIM, &Ks[0][0] + tid * 8 + c * 64 * 64);
    unsigned* vdst = (unsigned*)&Vs[0][0];
#pragma unroll
    for (int R = 0; R < 2; ++R) {
      const int sp = R * 32 + spw;
      unsigned o0 = __builtin_amdgcn_perm(vb[R].x, va[R].x, 0x05040100u);
      unsigned o1 = __builtin_amdgcn_perm(vb[R].x, va[R].x, 0x07060302u);
      unsigned o2 = __builtin_amdgcn_perm(vb[R].y, va[R].y, 0x05040100u);
      unsigned o3 = __builtin_amdgcn_perm(vb[R].y, va[R].y, 0x07060302u);
      const int sp2 = sp ^ swz;
      vdst[(4 * dq + 0) * 70 + sp2] = o0;
      vdst[(4 * dq + 1) * 70 + sp2] = o1;
      vdst[(4 * dq + 2) * 70 + sp2] = o2;
      vdst[(4 * dq + 3) * 70 + sp2] = o3;
    }
  }
  __syncthreads();

  for (int kb = 0; kb < 16; ++kb) {
    const int cur = kb & 1;
    const ushort_t* Kc = &Ks[cur][0];
    const ushort_t* Vc = &Vs[cur][0];

    /* 1+2. issue next tile: V global loads + K DMA into buf[cur^1] */
    uint2 va[2], vb[2];
    if (kb < 15) {
      const int kv1 = (kb + 1) * 128;
#pragma unroll
      for (int R = 0; R < 2; ++R) {
        const ushort_t* g = gV + (size_t)(kv1 + 2 * (R * 32 + spw)) * HDIM;
        va[R] = *(const uint2*)g;
        vb[R] = *(const uint2*)(g + HDIM);
      }
#pragma unroll
      for (int c = 0; c < 2; ++c)
        gload_lds16(gK + (size_t)(kv1 + c * 64) * HDIM,
                    &Ks[cur ^ 1][0] + tid * 8 + c * 64 * 64);
    }

    /* 3. S^T = K * Q^T on buf[cur]: key = c*16 + quad*4 + rg, q = lj.
       V-load latency drains under this compute. */
    floatx4 accST[8];
#pragma unroll
    for (int c = 0; c < 8; ++c) {
      const ushort_t* krow = Kc + (c * 16 + lj) * 64;
      bf16x8 kF0 = *(const bf16x8*)(krow + ((quad ^ swk) * 8));
      bf16x8 kF1 = *(const bf16x8*)(krow + (((quad ^ swk) ^ 4) * 8));
      floatx4 z = {0.f, 0.f, 0.f, 0.f};
      z = __builtin_amdgcn_mfma_f32_16x16x32_bf16(kF0, qF[0], z, 0, 0, 0);
      accST[c] = __builtin_amdgcn_mfma_f32_16x16x32_bf16(kF1, qF[1], z, 0, 0, 0);
    }

    /* no-max softmax: p = exp2(s) (scores pre-scaled by log2(e)/8 via Q) */
    shortx4 aP[8];
    float lsA = 0.f, lsB = 0.f;
#pragma unroll
    for (int c = 0; c < 8; ++c) {
      float p0 = fexp2(accST[c][0]);
      float p1 = fexp2(accST[c][1]);
      float p2 = fexp2(accST[c][2]);
      float p3 = fexp2(accST[c][3]);
      lsA += p0 + p1;
      lsB += p2 + p3;
      U32x2S4 t;
      t.u[0] = cvtpk(p0, p1);
      t.u[1] = cvtpk(p2, p3);
      aP[c] = t.s;
    }
    l_runA += lsA;
    l_runB += lsB;

    /* 4. write-late: V perm + stage into buf[cur^1] */
    if (kb < 15) {
      unsigned* vdst = (unsigned*)&Vs[cur ^ 1][0];
#pragma unroll
      for (int R = 0; R < 2; ++R) {
        const int sp = R * 32 + spw;
        unsigned o0 = __builtin_amdgcn_perm(vb[R].x, va[R].x, 0x05040100u);
        unsigned o1 = __builtin_amdgcn_perm(vb[R].x, va[R].x, 0x07060302u);
        unsigned o2 = __builtin_amdgcn_perm(vb[R].y, va[R].y, 0x05040100u);
        unsigned o3 = __builtin_amdgcn_perm(vb[R].y, va[R].y, 0x07060302u);
        const int sp2 = sp ^ swz;
        vdst[(4 * dq + 0) * 70 + sp2] = o0;
        vdst[(4 * dq + 1) * 70 + sp2] = o1;
        vdst[(4 * dq + 2) * 70 + sp2] = o2;
        vdst[(4 * dq + 3) * 70 + sp2] = o3;
      }
    }

    /* 5. O += P * V on buf[cur]; B-frag read applies V swizzle via quad^dt */
#pragma unroll
    for (int dt = 0; dt < 4; ++dt) {
      const ushort_t* vp = Vc + (dt * 16 + lj) * 140 + (quad ^ dt) * 4;
#pragma unroll
      for (int c = 0; c < 8; ++c) {
        shortx4 vF = *(const shortx4*)(vp + c * 16);
        accO[dt] = __builtin_amdgcn_mfma_f32_16x16x16bf16_1k(aP[c], vF, accO[dt], 0, 0, 0);
      }
    }

    /* 6. single barrier: next buf ready (DMA drained here), prev reads done */
    __syncthreads();
  }

  /* epilogue: O /= l, store fp32 in [b][h][s][d] flat */
  {
    float ls = l_runA + l_runB;
    ls += __shfl_xor(ls, 16, 64);
    ls += __shfl_xor(ls, 32, 64);
    const float inv = 1.0f / ls;
    const int sbase = (l & 48) | (quad * 4);
    float iv[4];
    iv[0] = __shfl(inv, sbase + 0, 64);
    iv[1] = __shfl(inv, sbase + 1, 64);
    iv[2] = __shfl(inv, sbase + 2, 64);
    iv[3] = __shfl(inv, sbase + 3, 64);
#pragma unroll
    for (int dt = 0; dt < 4; ++dt) {
#pragma unroll
      for (int rg = 0; rg < 4; ++rg) {
        const int q = q0 + quad * 4 + rg;
        out[headoff + (size_t)q * HDIM + dt * 16 + lj] = accO[dt][rg] * iv[rg];
      }
    }
  }
}

extern "C" void kernel_launch(void* const* d_in, const int* in_sizes, int n_in,
                              void* d_out, int out_size, void* d_ws, size_t ws_size,
                              hipStream_t stream) {
  (void)in_sizes; (void)n_in; (void)out_size; (void)ws_size;
  const float* x  = (const float*)d_in[0];
  const float* wq = (const float*)d_in[1];
  const float* bq = (const float*)d_in[2];
  float* out = (float*)d_out;

  char* ws = (char*)d_ws;
  ushort_t* Qb = (ushort_t*)(ws);
  ushort_t* Kb = (ushort_t*)(ws + 8388608);
  ushort_t* Vb = (ushort_t*)(ws + 16777216);
  ushort_t* Xb = (ushort_t*)(ws + 25165824);
  ushort_t* Wb = (ushort_t*)(ws + 33554432);

  cvt_bf16_kernel<<<3584, 256, 0, stream>>>(x, wq, Xb, Wb);
  qkv_gemm_kernel<<<dim3(N_COLS / 128, M_ROWS / 128), 256, 0, stream>>>(Xb, Wb, bq, Qb, Kb, Vb);
  attn_kernel<<<512, 512, 0, stream>>>(Qb, Kb, Vb, out);
}

// Round 8
// 160.419 us; speedup vs baseline: 1.0230x; 1.0230x over previous
//
#include <hip/hip_runtime.h>
#include <cstdint>

typedef unsigned short ushort_t;

#define M_ROWS 4096
#define N_COLS 3072
#define K_DIM  1024
#define S_LEN  2048
#define NHEADS 16
#define HDIM   64
#define QSCALE 0.1803368801111204f  /* (1/sqrt(64)) * log2(e) */

typedef __bf16 bf16_t;
typedef bf16_t  bf16x8  __attribute__((ext_vector_type(8)));
typedef short   shortx4 __attribute__((ext_vector_type(4)));
typedef float   floatx4 __attribute__((ext_vector_type(4)));
typedef ushort_t ushortx4 __attribute__((ext_vector_type(4)));

union U32x2S4 { unsigned u[2]; shortx4 s; };

__device__ __forceinline__ unsigned short f2bf(float f) {
  unsigned u = __float_as_uint(f);
  u += 0x7FFFu + ((u >> 16) & 1u);
  return (unsigned short)(u >> 16);
}

// pack two fp32 -> two bf16 in one u32: low=a, high=b (fallback: round-half-up)
__device__ __forceinline__ unsigned pkbf(float a, float b) {
  unsigned ua = __float_as_uint(a) + 0x8000u;
  unsigned ub = __float_as_uint(b) + 0x8000u;
  return __builtin_amdgcn_perm(ub, ua, 0x07060302u);
}

// packed bf16 convert: single v_cvt_pk_bf16_f32 on gfx950 if available
__device__ __forceinline__ unsigned cvtpk(float a, float b) {
#if __has_builtin(__builtin_amdgcn_cvt_pk_bf16_f32)
  auto t = __builtin_amdgcn_cvt_pk_bf16_f32(a, b);
  unsigned r;
  __builtin_memcpy(&r, &t, 4);
  return r;
#else
  return pkbf(a, b);
#endif
}

__device__ __forceinline__ float fexp2(float x) {
#if __has_builtin(__builtin_amdgcn_exp2f)
  return __builtin_amdgcn_exp2f(x);
#else
  float r; asm volatile("v_exp_f32 %0, %1\n\ts_nop 1" : "=v"(r) : "v"(x)); return r;
#endif
}

__device__ __forceinline__ void gload_lds16(const void* g, void* l) {
  __builtin_amdgcn_global_load_lds(
      (const __attribute__((address_space(1))) unsigned int*)g,
      (__attribute__((address_space(3))) unsigned int*)l,
      16, 0, 0);
}

/* ------------------------ fp32 -> bf16 convert (v2: 32B/thread) ---------- */
__global__ __launch_bounds__(256) void cvt_bf16_kernel(
    const float* __restrict__ x, const float* __restrict__ w,
    ushort_t* __restrict__ Xb, ushort_t* __restrict__ Wb) {
  const int NX8 = (M_ROWS * K_DIM) / 8;
  int i = blockIdx.x * 256 + threadIdx.x;
  const float4* src;
  ushort_t* dst;
  int idx;
  if (i < NX8) { src = (const float4*)x; dst = Xb; idx = i; }
  else         { src = (const float4*)w; dst = Wb; idx = i - NX8; }
  float4 a = src[2 * idx];
  float4 b = src[2 * idx + 1];
  uint4 o;
  o.x = cvtpk(a.x, a.y);
  o.y = cvtpk(a.z, a.w);
  o.z = cvtpk(b.x, b.y);
  o.w = cvtpk(b.z, b.w);
  *(uint4*)(dst + 8 * (size_t)idx) = o;
}

/* ------------------------ QKV GEMM (r3 version — empirically best) --------
   m97 structure + LDS XOR chunk swizzle (chunk' = chunk ^ (row&7)),
   conflict-free (verified r3: SQ_LDS_BANK_CONFLICT -> 0). Scalar-store
   epilogue; r4's "vectorized" variant coincided with +13us rest — reverted.
   DO NOT MODIFY without counters (surfaces in top-5 once attn < gemm). */
__global__ __launch_bounds__(256) void qkv_gemm_kernel(
    const ushort_t* __restrict__ Xb, const ushort_t* __restrict__ Wb,
    const float* __restrict__ bias,
    ushort_t* __restrict__ Qb, ushort_t* __restrict__ Kb, ushort_t* __restrict__ Vb) {
  __shared__ ushort_t As[128 * 64];
  __shared__ ushort_t Bs[128 * 64];
  const int tid = threadIdx.x;
  const int l = tid & 63, w = tid >> 6;
  const int quad = l >> 4, lj = l & 15;
  const int m0 = blockIdx.y * 128, n0 = blockIdx.x * 128;
  const int wm = (w & 1) * 64, wn = (w >> 1) * 64;

  floatx4 acc[4][4] = {};

  const int srow = w * 32 + (l >> 3);
  const int scol = ((l & 7) ^ (l >> 3)) * 8; /* swizzled source chunk */
  const ushort_t* gA = Xb + (size_t)(m0 + srow) * K_DIM + scol;
  const ushort_t* gB = Wb + (size_t)(n0 + srow) * K_DIM + scol;
  ushort_t* lA = As + (w * 32) * 64;
  ushort_t* lB = Bs + (w * 32) * 64;

  const int swr = lj & 7;

  for (int k0 = 0; k0 < K_DIM; k0 += 64) {
    __syncthreads();
#pragma unroll
    for (int c = 0; c < 4; ++c) {
      gload_lds16(gA + (size_t)(c * 8) * K_DIM + k0, lA + c * 8 * 64);
      gload_lds16(gB + (size_t)(c * 8) * K_DIM + k0, lB + c * 8 * 64);
    }
    __syncthreads();
#pragma unroll
    for (int kk = 0; kk < 2; ++kk) {
      const int ch = ((kk * 4 + quad) ^ swr) * 8;
      bf16x8 aF[4], bF[4];
#pragma unroll
      for (int i = 0; i < 4; ++i)
        aF[i] = *(const bf16x8*)(As + (wm + i * 16 + lj) * 64 + ch);
#pragma unroll
      for (int j = 0; j < 4; ++j)
        bF[j] = *(const bf16x8*)(Bs + (wn + j * 16 + lj) * 64 + ch);
#pragma unroll
      for (int i = 0; i < 4; ++i)
#pragma unroll
        for (int j = 0; j < 4; ++j)
          acc[i][j] = __builtin_amdgcn_mfma_f32_16x16x32_bf16(aF[i], bF[j], acc[i][j], 0, 0, 0);
    }
  }

  /* epilogue: n = h*192 + r; r<64 -> Q, r<128 -> K, else V */
#pragma unroll
  for (int j = 0; j < 4; ++j) {
    const int n = n0 + wn + j * 16 + lj;
    const int h = n / 192;
    const int r = n - h * 192;
    const int seg = r >> 6;
    const int d = r & 63;
    const float bv = bias[n];
    ushort_t* dst = (seg == 0) ? Qb : (seg == 1) ? Kb : Vb;
    const float scl = (seg == 0) ? QSCALE : 1.0f;
    const size_t base = (size_t)h * S_LEN * HDIM + d;
#pragma unroll
    for (int i = 0; i < 4; ++i) {
#pragma unroll
      for (int rg = 0; rg < 4; ++rg) {
        const int m = m0 + wm + i * 16 + quad * 4 + rg;
        const int bi = m >> 11;
        const int si = m & 2047;
        dst[base + ((size_t)bi * NHEADS * S_LEN + si) * HDIM] =
            f2bf((acc[i][j][rg] + bv) * scl);
      }
    }
  }
}

/* ------------------------ flash attention (v11: 32q/wave) -----------------
   HISTORY: v4.1 = 53.2us (2 barriers). v5-v8 K-from-global = 137-154
   (structurally dead). v9 +setprio = 55.6 (removed). v10 dbuf single-
   barrier = 53.5us with LDS pipe at ~96% of roofline: per wave-iter
   K 16xb128(192cy) + V 32xb64(224) + Vwrite 8xb32(48) + K-DMA(16)
   ~ 480cy x 16 waves x 16 iters ~ 51us/CU ~= observed. LDS-throughput-
   bound: only FEWER LDS CYCLES PER WORK helps now.
   v11: 32q/wave. Every wave reads the full K/V tile per iter no matter
   how many q it owns -> doubling q/wave halves LDS read cycles per q.
   Block stays 512 threads (staging byte-identical); grid 512 -> 256
   (256q/block); compute gains qh dim: K/V fragments loaded ONCE, used
   for both q-halves. New LDS budget ~4.4kcy/iter/CU -> ~29us floor.
   r5 lesson ("32q regressed 2x") was on the OLD serial 2-barrier
   structure where 8 waves/CU couldn't hide exposed staging latency;
   v10's issue-early/write-late pipeline hides it programmatically, and
   grid 256 = 1 block/CU makes VGPR<=256 free (2 waves/SIMD fixed).
   PREDICT: attn 53.5 -> 33-40us, VGPR ~150-200, MfmaUtil 38 -> 50-60,
   Occupancy ~17-25% (intentional), FETCH ~12.3MB, conflicts 0.
   FALSIFIER: attn >= 50 => TLP loss dominates; revert to v10 + V-b128. */
__global__ __launch_bounds__(512, 2) void attn_kernel(
    const ushort_t* __restrict__ Qb, const ushort_t* __restrict__ Kb,
    const ushort_t* __restrict__ Vb, float* __restrict__ out) {
  __shared__ ushort_t Ks[2][128 * 64];
  __shared__ ushort_t Vs[2][64 * 140];
  const int tid = threadIdx.x;
  const int l = tid & 63, w = tid >> 6;
  const int quad = l >> 4, lj = l & 15;
  /* XCD swizzle: HW round-robins wg -> XCD (idx%8). 256 blocks -> XCD x
     gets ids [x*32, x*32+32) = bh 4x..4x+3 (8 q-tiles each) -> per-XCD
     K/V working set ~2MB, L2-resident. 256%8==0 -> bijective. */
  const int id = (blockIdx.x & 7) * 32 + (blockIdx.x >> 3);
  const int bh = id >> 3;
  const int qt = id & 7;
  const int q0 = qt * 256 + w * 32;
  const size_t headoff = (size_t)bh * S_LEN * HDIM;

  /* Q fragments: B-operand, n=q=lj (+qh*16), k = kk*32 + quad*8 + j */
  bf16x8 qF[2][2];
#pragma unroll
  for (int qh = 0; qh < 2; ++qh)
#pragma unroll
    for (int kk = 0; kk < 2; ++kk)
      qF[qh][kk] = *(const bf16x8*)(Qb + headoff +
                                    (size_t)(q0 + qh * 16 + lj) * HDIM +
                                    kk * 32 + quad * 8);

  floatx4 accO[2][4] = {};
  float l_runA[2] = {0.f, 0.f}, l_runB[2] = {0.f, 0.f};

  /* K staging with swizzled source chunk; LDS dest stays lane-contiguous */
  const int kr = tid >> 3;
  const int kc = ((tid & 7) ^ (kr & 7)) * 8;
  const ushort_t* gK = Kb + headoff + (size_t)kr * HDIM + kc;

  /* V staging: thread covers (s pair 2sp..2sp+1) x (d quad 4dq..4dq+3), R=0,1 */
  const int dq = tid & 15;
  const int spw = tid >> 4; /* 0..31 */
  const ushort_t* gV = Vb + headoff + dq * 4;
  const int swz = (dq >> 2) << 1; /* V swizzle in u32-column units */

  const int swk = lj & 7;

  /* ---- prologue: stage tile 0 into buffer 0 ---- */
  {
    uint2 va[2], vb[2];
#pragma unroll
    for (int R = 0; R < 2; ++R) {
      const ushort_t* g = gV + (size_t)(2 * (R * 32 + spw)) * HDIM;
      va[R] = *(const uint2*)g;
      vb[R] = *(const uint2*)(g + HDIM);
    }
#pragma unroll
    for (int c = 0; c < 2; ++c)
      gload_lds16(gK + (size_t)(c * 64) * HDIM, &Ks[0][0] + tid * 8 + c * 64 * 64);
    unsigned* vdst = (unsigned*)&Vs[0][0];
#pragma unroll
    for (int R = 0; R < 2; ++R) {
      const int sp = R * 32 + spw;
      unsigned o0 = __builtin_amdgcn_perm(vb[R].x, va[R].x, 0x05040100u);
      unsigned o1 = __builtin_amdgcn_perm(vb[R].x, va[R].x, 0x07060302u);
      unsigned o2 = __builtin_amdgcn_perm(vb[R].y, va[R].y, 0x05040100u);
      unsigned o3 = __builtin_amdgcn_perm(vb[R].y, va[R].y, 0x07060302u);
      const int sp2 = sp ^ swz;
      vdst[(4 * dq + 0) * 70 + sp2] = o0;
      vdst[(4 * dq + 1) * 70 + sp2] = o1;
      vdst[(4 * dq + 2) * 70 + sp2] = o2;
      vdst[(4 * dq + 3) * 70 + sp2] = o3;
    }
  }
  __syncthreads();

  for (int kb = 0; kb < 16; ++kb) {
    const int cur = kb & 1;
    const ushort_t* Kc = &Ks[cur][0];
    const ushort_t* Vc = &Vs[cur][0];

    /* 1+2. issue next tile: V global loads + K DMA into buf[cur^1] */
    uint2 va[2], vb[2];
    if (kb < 15) {
      const int kv1 = (kb + 1) * 128;
#pragma unroll
      for (int R = 0; R < 2; ++R) {
        const ushort_t* g = gV + (size_t)(kv1 + 2 * (R * 32 + spw)) * HDIM;
        va[R] = *(const uint2*)g;
        vb[R] = *(const uint2*)(g + HDIM);
      }
#pragma unroll
      for (int c = 0; c < 2; ++c)
        gload_lds16(gK + (size_t)(kv1 + c * 64) * HDIM,
                    &Ks[cur ^ 1][0] + tid * 8 + c * 64 * 64);
    }

    /* 3. S^T = K * Q^T on buf[cur]: key = c*16 + quad*4 + rg,
       q = q0 + qh*16 + lj. K fragments loaded ONCE, used for both qh.
       V-load latency drains under this compute. */
    floatx4 accST[2][8];
#pragma unroll
    for (int c = 0; c < 8; ++c) {
      const ushort_t* krow = Kc + (c * 16 + lj) * 64;
      bf16x8 kF0 = *(const bf16x8*)(krow + ((quad ^ swk) * 8));
      bf16x8 kF1 = *(const bf16x8*)(krow + (((quad ^ swk) ^ 4) * 8));
#pragma unroll
      for (int qh = 0; qh < 2; ++qh) {
        floatx4 z = {0.f, 0.f, 0.f, 0.f};
        z = __builtin_amdgcn_mfma_f32_16x16x32_bf16(kF0, qF[qh][0], z, 0, 0, 0);
        accST[qh][c] =
            __builtin_amdgcn_mfma_f32_16x16x32_bf16(kF1, qF[qh][1], z, 0, 0, 0);
      }
    }

    /* no-max softmax: p = exp2(s) (scores pre-scaled by log2(e)/8 via Q) */
    shortx4 aP[2][8];
#pragma unroll
    for (int qh = 0; qh < 2; ++qh) {
      float lsA = 0.f, lsB = 0.f;
#pragma unroll
      for (int c = 0; c < 8; ++c) {
        float p0 = fexp2(accST[qh][c][0]);
        float p1 = fexp2(accST[qh][c][1]);
        float p2 = fexp2(accST[qh][c][2]);
        float p3 = fexp2(accST[qh][c][3]);
        lsA += p0 + p1;
        lsB += p2 + p3;
        U32x2S4 t;
        t.u[0] = cvtpk(p0, p1);
        t.u[1] = cvtpk(p2, p3);
        aP[qh][c] = t.s;
      }
      l_runA[qh] += lsA;
      l_runB[qh] += lsB;
    }

    /* 4. write-late: V perm + stage into buf[cur^1] */
    if (kb < 15) {
      unsigned* vdst = (unsigned*)&Vs[cur ^ 1][0];
#pragma unroll
      for (int R = 0; R < 2; ++R) {
        const int sp = R * 32 + spw;
        unsigned o0 = __builtin_amdgcn_perm(vb[R].x, va[R].x, 0x05040100u);
        unsigned o1 = __builtin_amdgcn_perm(vb[R].x, va[R].x, 0x07060302u);
        unsigned o2 = __builtin_amdgcn_perm(vb[R].y, va[R].y, 0x05040100u);
        unsigned o3 = __builtin_amdgcn_perm(vb[R].y, va[R].y, 0x07060302u);
        const int sp2 = sp ^ swz;
        vdst[(4 * dq + 0) * 70 + sp2] = o0;
        vdst[(4 * dq + 1) * 70 + sp2] = o1;
        vdst[(4 * dq + 2) * 70 + sp2] = o2;
        vdst[(4 * dq + 3) * 70 + sp2] = o3;
      }
    }

    /* 5. O += P * V on buf[cur]; vF loaded ONCE, used for both qh */
#pragma unroll
    for (int dt = 0; dt < 4; ++dt) {
      const ushort_t* vp = Vc + (dt * 16 + lj) * 140 + (quad ^ dt) * 4;
#pragma unroll
      for (int c = 0; c < 8; ++c) {
        shortx4 vF = *(const shortx4*)(vp + c * 16);
        accO[0][dt] =
            __builtin_amdgcn_mfma_f32_16x16x16bf16_1k(aP[0][c], vF, accO[0][dt], 0, 0, 0);
        accO[1][dt] =
            __builtin_amdgcn_mfma_f32_16x16x16bf16_1k(aP[1][c], vF, accO[1][dt], 0, 0, 0);
      }
    }

    /* 6. single barrier: next buf ready (DMA drained here), prev reads done */
    __syncthreads();
  }

  /* epilogue: O /= l, store fp32 in [b][h][s][d] flat */
#pragma unroll
  for (int qh = 0; qh < 2; ++qh) {
    float ls = l_runA[qh] + l_runB[qh];
    ls += __shfl_xor(ls, 16, 64);
    ls += __shfl_xor(ls, 32, 64);
    const float inv = 1.0f / ls;
    const int sbase = (l & 48) | (quad * 4);
    float iv[4];
    iv[0] = __shfl(inv, sbase + 0, 64);
    iv[1] = __shfl(inv, sbase + 1, 64);
    iv[2] = __shfl(inv, sbase + 2, 64);
    iv[3] = __shfl(inv, sbase + 3, 64);
#pragma unroll
    for (int dt = 0; dt < 4; ++dt) {
#pragma unroll
      for (int rg = 0; rg < 4; ++rg) {
        const int q = q0 + qh * 16 + quad * 4 + rg;
        out[headoff + (size_t)q * HDIM + dt * 16 + lj] = accO[qh][dt][rg] * iv[rg];
      }
    }
  }
}

extern "C" void kernel_launch(void* const* d_in, const int* in_sizes, int n_in,
                              void* d_out, int out_size, void* d_ws, size_t ws_size,
                              hipStream_t stream) {
  (void)in_sizes; (void)n_in; (void)out_size; (void)ws_size;
  const float* x  = (const float*)d_in[0];
  const float* wq = (const float*)d_in[1];
  const float* bq = (const float*)d_in[2];
  float* out = (float*)d_out;

  char* ws = (char*)d_ws;
  ushort_t* Qb = (ushort_t*)(ws);
  ushort_t* Kb = (ushort_t*)(ws + 8388608);
  ushort_t* Vb = (ushort_t*)(ws + 16777216);
  ushort_t* Xb = (ushort_t*)(ws + 25165824);
  ushort_t* Wb = (ushort_t*)(ws + 33554432);

  cvt_bf16_kernel<<<3584, 256, 0, stream>>>(x, wq, Xb, Wb);
  qkv_gemm_kernel<<<dim3(N_COLS / 128, M_ROWS / 128), 256, 0, stream>>>(Xb, Wb, bq, Qb, Kb, Vb);
  attn_kernel<<<256, 512, 0, stream>>>(Qb, Kb, Vb, out);
}